// Round 1
// baseline (3356.798 us; speedup 1.0000x reference)
//
#include <hip/hip_runtime.h>
#include <hip/hip_bf16.h>

#define T_SEQ 1024
#define D_MODEL 512
#define N_HEADS 8
#define D_HEAD 64
#define SCALE_C 0.125f   // 1/sqrt(64)

// ---------------------------------------------------------------------------
// Generic tiled fp32 GEMM: C[M,N] = A[M,K] @ W[K,N] (+ bias[N])
// 64x64 tile, BK=16, 256 threads, 4x4 micro-tile per thread.
// ---------------------------------------------------------------------------
__global__ __launch_bounds__(256) void gemm_bias_kernel(
    const float* __restrict__ A, const float* __restrict__ W,
    const float* __restrict__ bias, float* __restrict__ C,
    int M, int N, int K)
{
    const int tid  = threadIdx.x;
    const int row0 = blockIdx.y * 64;
    const int col0 = blockIdx.x * 64;

    __shared__ float As[16][64 + 1];   // [k][m]
    __shared__ float Bs[16][64 + 1];   // [k][n]

    const int ty = tid >> 4;   // 0..15  -> output rows ty*4..ty*4+3
    const int tx = tid & 15;   // 0..15  -> output cols tx*4..tx*4+3

    float acc[4][4] = {};

    for (int k0 = 0; k0 < K; k0 += 16) {
        // A tile: 64 rows x 16 k
        #pragma unroll
        for (int l = 0; l < 4; ++l) {
            int idx = tid + l * 256;        // 0..1023
            int r   = idx >> 4;             // 0..63
            int kk  = idx & 15;             // 0..15
            int gr  = row0 + r;
            As[kk][r] = (gr < M) ? A[(size_t)gr * K + k0 + kk] : 0.f;
        }
        // W tile: 16 k x 64 n
        #pragma unroll
        for (int l = 0; l < 4; ++l) {
            int idx = tid + l * 256;
            int kk  = idx >> 6;             // 0..15
            int c   = idx & 63;             // 0..63
            Bs[kk][c] = W[(size_t)(k0 + kk) * N + col0 + c];
        }
        __syncthreads();

        #pragma unroll
        for (int kk = 0; kk < 16; ++kk) {
            float a[4], bv[4];
            #pragma unroll
            for (int i = 0; i < 4; ++i) a[i]  = As[kk][ty * 4 + i];
            #pragma unroll
            for (int j = 0; j < 4; ++j) bv[j] = Bs[kk][tx * 4 + j];
            #pragma unroll
            for (int i = 0; i < 4; ++i)
                #pragma unroll
                for (int j = 0; j < 4; ++j)
                    acc[i][j] += a[i] * bv[j];
        }
        __syncthreads();
    }

    #pragma unroll
    for (int i = 0; i < 4; ++i) {
        int gr = row0 + ty * 4 + i;
        if (gr >= M) continue;
        #pragma unroll
        for (int j = 0; j < 4; ++j) {
            int gc = col0 + tx * 4 + j;
            float v = acc[i][j];
            if (bias) v += bias[gc];
            C[(size_t)gr * N + gc] = v;
        }
    }
}

// ---------------------------------------------------------------------------
// Flash-style relative-position attention.
// Block: (b, h, 32-query tile). 256 threads = 32 rows x 8 lanes.
// score[t,s] = SCALE*((q+u).k[s] + (q+v).p[s + 1023 - t])  (rel-shift fused)
// Q/K/V layout: [b*1024 + t][h*64 + d] row-major 512.  P: [n][h*64+d], n<2047.
// ---------------------------------------------------------------------------
__global__ __launch_bounds__(256) void attn_kernel(
    const float* __restrict__ Q, const float* __restrict__ K,
    const float* __restrict__ V, const float* __restrict__ P,
    const float* __restrict__ bias_u, const float* __restrict__ bias_v,
    float* __restrict__ O)
{
    const int tid = threadIdx.x;
    const int t0  = blockIdx.x * 32;
    const int h   = blockIdx.y;
    const int b   = blockIdx.z;
    const int ty  = tid >> 3;    // 0..31 : query row within tile
    const int tx  = tid & 7;     // 0..7

    __shared__ float Qu[32][65];
    __shared__ float Qv[32][65];
    __shared__ float Kt[64][65];
    __shared__ float Vt[64][65];
    __shared__ float S [32][65];

    // load Q tile, add position biases
    for (int idx = tid; idx < 32 * 64; idx += 256) {
        int r = idx >> 6, d = idx & 63;
        float q = Q[((size_t)(b * T_SEQ + t0 + r)) * D_MODEL + h * D_HEAD + d];
        Qu[r][d] = q + bias_u[h * D_HEAD + d];
        Qv[r][d] = q + bias_v[h * D_HEAD + d];
    }

    float m_run = -1e30f, l_run = 0.f;
    float Oacc[8] = {0.f, 0.f, 0.f, 0.f, 0.f, 0.f, 0.f, 0.f};

    const float* Ph = P + h * D_HEAD;
    const int t = t0 + ty;

    for (int s0 = 0; s0 < T_SEQ; s0 += 64) {
        __syncthreads();   // protect Kt/Vt reuse (and first-iter Qu/Qv)
        for (int idx = tid; idx < 64 * 64; idx += 256) {
            int r = idx >> 6, d = idx & 63;
            size_t g = ((size_t)(b * T_SEQ + s0 + r)) * D_MODEL + h * D_HEAD + d;
            Kt[r][d] = K[g];
            Vt[r][d] = V[g];
        }
        __syncthreads();

        // --- scores: row t, s = s0 + tx*8 + i ---
        float sc[8];
        #pragma unroll
        for (int i = 0; i < 8; ++i) {
            int sl = tx * 8 + i;
            int s  = s0 + sl;
            int pr = s + (T_SEQ - 1) - t;        // 0..2046
            const float4* p4 = (const float4*)(Ph + (size_t)pr * D_MODEL);
            float accc = 0.f, accp = 0.f;
            #pragma unroll
            for (int d = 0; d < 64; ++d)
                accc += Qu[ty][d] * Kt[sl][d];
            #pragma unroll
            for (int d4 = 0; d4 < 16; ++d4) {
                float4 pv = p4[d4];
                accp += Qv[ty][d4 * 4 + 0] * pv.x + Qv[ty][d4 * 4 + 1] * pv.y
                      + Qv[ty][d4 * 4 + 2] * pv.z + Qv[ty][d4 * 4 + 3] * pv.w;
            }
            sc[i] = (accc + accp) * SCALE_C;
        }

        // --- online softmax, row reduction across the 8 lanes of this row ---
        float mloc = sc[0];
        #pragma unroll
        for (int i = 1; i < 8; ++i) mloc = fmaxf(mloc, sc[i]);
        #pragma unroll
        for (int off = 1; off < 8; off <<= 1)
            mloc = fmaxf(mloc, __shfl_xor(mloc, off));
        float m_new = fmaxf(m_run, mloc);
        float alpha = __expf(m_run - m_new);
        float psum = 0.f;
        #pragma unroll
        for (int i = 0; i < 8; ++i) {
            float e = __expf(sc[i] - m_new);
            S[ty][tx * 8 + i] = e;
            psum += e;
        }
        #pragma unroll
        for (int off = 1; off < 8; off <<= 1)
            psum += __shfl_xor(psum, off);
        l_run = l_run * alpha + psum;
        m_run = m_new;
        #pragma unroll
        for (int j = 0; j < 8; ++j) Oacc[j] *= alpha;

        // --- PV: same-wave S rows, no barrier needed ---
        #pragma unroll
        for (int sl = 0; sl < 64; ++sl) {
            float p = S[ty][sl];
            #pragma unroll
            for (int j = 0; j < 8; ++j)
                Oacc[j] += p * Vt[sl][tx * 8 + j];
        }
    }

    float inv_l = 1.0f / l_run;
    size_t base = ((size_t)(b * T_SEQ + t0 + ty)) * D_MODEL + h * D_HEAD + tx * 8;
    #pragma unroll
    for (int j = 0; j < 8; ++j)
        O[base + j] = Oacc[j] * inv_l;
}

// ---------------------------------------------------------------------------
extern "C" void kernel_launch(void* const* d_in, const int* in_sizes, int n_in,
                              void* d_out, int out_size, void* d_ws, size_t ws_size,
                              hipStream_t stream) {
    const float* x       = (const float*)d_in[0];   // (8,1024,512)
    const float* pos_enc = (const float*)d_in[1];   // (1,2047,512)
    const float* Wq      = (const float*)d_in[2];
    const float* bq      = (const float*)d_in[3];
    const float* Wk      = (const float*)d_in[4];
    const float* bk      = (const float*)d_in[5];
    const float* Wv      = (const float*)d_in[6];
    const float* bv      = (const float*)d_in[7];
    const float* Wpos    = (const float*)d_in[8];
    const float* pbu     = (const float*)d_in[9];   // (8,64)
    const float* pbv     = (const float*)d_in[10];  // (8,64)
    const float* Wo      = (const float*)d_in[11];
    const float* bo      = (const float*)d_in[12];
    float* out = (float*)d_out;

    const size_t M  = 8 * T_SEQ;            // 8192
    const size_t SZ = M * D_MODEL;          // 4,194,304 floats
    float* ws = (float*)d_ws;
    float* Qb = ws;
    float* Kb = Qb + SZ;
    float* Vb = Kb + SZ;
    float* Pb = Vb + SZ;                    // 2047*512 used
    float* AO = Pb + (size_t)2048 * D_MODEL;

    dim3 blk(256);
    dim3 gqkv(D_MODEL / 64, M / 64);        // (8,128)
    hipLaunchKernelGGL(gemm_bias_kernel, gqkv, blk, 0, stream, x, Wq, bq, Qb, (int)M, D_MODEL, D_MODEL);
    hipLaunchKernelGGL(gemm_bias_kernel, gqkv, blk, 0, stream, x, Wk, bk, Kb, (int)M, D_MODEL, D_MODEL);
    hipLaunchKernelGGL(gemm_bias_kernel, gqkv, blk, 0, stream, x, Wv, bv, Vb, (int)M, D_MODEL, D_MODEL);

    dim3 gp(D_MODEL / 64, (2047 + 63) / 64);  // (8,32)
    hipLaunchKernelGGL(gemm_bias_kernel, gp, blk, 0, stream, pos_enc, Wpos, (const float*)nullptr, Pb, 2047, D_MODEL, D_MODEL);

    dim3 ga(T_SEQ / 32, N_HEADS, 8);        // (32,8,8)
    hipLaunchKernelGGL(attn_kernel, ga, blk, 0, stream, Qb, Kb, Vb, Pb, pbu, pbv, AO);

    hipLaunchKernelGGL(gemm_bias_kernel, gqkv, blk, 0, stream, AO, Wo, bo, out, (int)M, D_MODEL, D_MODEL);
}

// Round 2
// 360.921 us; speedup vs baseline: 9.3007x; 9.3007x over previous
//
#include <hip/hip_runtime.h>
#include <hip/hip_bf16.h>

#define T_SEQ 1024
#define D_MODEL 512
#define N_HEADS 8
#define D_HEAD 64

typedef unsigned short ushort_t;
typedef short s16x8 __attribute__((ext_vector_type(8)));
typedef float f32x4 __attribute__((ext_vector_type(4)));

__device__ inline f32x4 mfma16(s16x8 a, s16x8 b, f32x4 c) {
    return __builtin_amdgcn_mfma_f32_16x16x32_bf16(a, b, c, 0, 0, 0);
}

__device__ inline ushort_t f2bf(float f) {   // RTNE float->bf16
    union { float f; unsigned u; } v; v.f = f;
    unsigned r = v.u + 0x7FFFu + ((v.u >> 16) & 1u);
    return (ushort_t)(r >> 16);
}

__device__ inline void cvt4(const float4 f, ushort_t* t) {
    t[0] = f2bf(f.x); t[1] = f2bf(f.y); t[2] = f2bf(f.z); t[3] = f2bf(f.w);
}
__device__ inline s16x8 pack8(const ushort_t* t) {
    s16x8 r;
    #pragma unroll
    for (int e = 0; e < 8; ++e) r[e] = (short)t[e];
    return r;
}

// ---------------------------------------------------------------------------
// Transpose+cast weights: WT[z][n][k] = bf16(W[k][n]), 512x512 each, z=0..3
// ---------------------------------------------------------------------------
__global__ __launch_bounds__(256) void transpose_cast_w(
    const float* __restrict__ W0, const float* __restrict__ W1,
    const float* __restrict__ W2, const float* __restrict__ W3,
    ushort_t* __restrict__ WT)
{
    const float* W = (blockIdx.z == 0) ? W0 : (blockIdx.z == 1) ? W1
                   : (blockIdx.z == 2) ? W2 : W3;
    __shared__ float T[64][68];
    const int n0 = blockIdx.x * 64, k0 = blockIdx.y * 64;
    const int tid = threadIdx.x;
    const int rr = tid >> 2, cc = (tid & 3) * 16;

    const float* src = W + (size_t)(k0 + rr) * 512 + n0 + cc;
    *(float4*)&T[rr][cc + 0]  = *(const float4*)(src);
    *(float4*)&T[rr][cc + 4]  = *(const float4*)(src + 4);
    *(float4*)&T[rr][cc + 8]  = *(const float4*)(src + 8);
    *(float4*)&T[rr][cc + 12] = *(const float4*)(src + 12);
    __syncthreads();

    ushort_t tmp[16];
    #pragma unroll
    for (int e = 0; e < 16; ++e) tmp[e] = f2bf(T[cc + e][rr]);
    ushort_t* dst = WT + ((size_t)blockIdx.z * 512 + n0 + rr) * 512 + k0 + cc;
    *(s16x8*)dst       = pack8(tmp);
    *(s16x8*)(dst + 8) = pack8(tmp + 8);
}

// ---------------------------------------------------------------------------
// Fused Q/K/V MFMA GEMM.  A fp32 [8192][512] (cast to bf16 in staging),
// WT bf16 [3][512][512] ([set][n][k]).  Tile 64x64, BK=64, 4 waves.
// Q epilogue writes Qu=(acc+bq+pbu)*0.125 and Qv=(acc+bq+pbv)*0.125 as bf16.
// ---------------------------------------------------------------------------
__global__ __launch_bounds__(256) void gemm_qkv_fused(
    const float* __restrict__ A, const ushort_t* __restrict__ WT,
    const float* __restrict__ bq, const float* __restrict__ bk,
    const float* __restrict__ bv,
    const float* __restrict__ pbu, const float* __restrict__ pbv,
    ushort_t* __restrict__ Qu, ushort_t* __restrict__ Qv,
    ushort_t* __restrict__ Ko, ushort_t* __restrict__ Vo)
{
    const int tid = threadIdx.x;
    const int col0 = blockIdx.x * 64;
    const int row0 = blockIdx.y * 64;
    const int w = tid >> 6, lane = tid & 63;
    const int quad = lane >> 4, lanelo = lane & 15;
    const int sr = tid >> 2, sc = (tid & 3) * 16;

    __shared__ ushort_t As[64][72];
    __shared__ ushort_t Ws[3][64][72];

    f32x4 acc[3][4] = {};

    for (int k0 = 0; k0 < 512; k0 += 64) {
        __syncthreads();
        {   // stage A (fp32 -> bf16)
            const float* ap = A + (size_t)(row0 + sr) * 512 + k0 + sc;
            ushort_t tmp[16];
            cvt4(*(const float4*)(ap + 0),  tmp + 0);
            cvt4(*(const float4*)(ap + 4),  tmp + 4);
            cvt4(*(const float4*)(ap + 8),  tmp + 8);
            cvt4(*(const float4*)(ap + 12), tmp + 12);
            *(s16x8*)&As[sr][sc]     = pack8(tmp);
            *(s16x8*)&As[sr][sc + 8] = pack8(tmp + 8);
        }
        #pragma unroll
        for (int s = 0; s < 3; ++s) {   // stage W^T tiles (already bf16 [n][k])
            const ushort_t* wp = WT + ((size_t)(s * 512 + col0 + sr)) * 512 + k0 + sc;
            *(s16x8*)&Ws[s][sr][sc]     = *(const s16x8*)wp;
            *(s16x8*)&Ws[s][sr][sc + 8] = *(const s16x8*)(wp + 8);
        }
        __syncthreads();

        #pragma unroll
        for (int ks = 0; ks < 2; ++ks) {
            s16x8 af = *(const s16x8*)&As[16 * w + lanelo][ks * 32 + quad * 8];
            #pragma unroll
            for (int s = 0; s < 3; ++s)
                #pragma unroll
                for (int tn = 0; tn < 4; ++tn) {
                    s16x8 bf = *(const s16x8*)&Ws[s][tn * 16 + lanelo][ks * 32 + quad * 8];
                    acc[s][tn] = mfma16(af, bf, acc[s][tn]);
                }
        }
    }

    #pragma unroll
    for (int tn = 0; tn < 4; ++tn) {
        int col = col0 + tn * 16 + lanelo;
        float vbq = bq[col], vbu = pbu[col], vbv = pbv[col];
        float vbk = bk[col], vbb = bv[col];
        #pragma unroll
        for (int r = 0; r < 4; ++r) {
            int row = row0 + 16 * w + 4 * quad + r;
            size_t o = (size_t)row * 512 + col;
            float aq = acc[0][tn][r] + vbq;
            Qu[o] = f2bf((aq + vbu) * 0.125f);
            Qv[o] = f2bf((aq + vbv) * 0.125f);
            Ko[o] = f2bf(acc[1][tn][r] + vbk);
            Vo[o] = f2bf(acc[2][tn][r] + vbb);
        }
    }
}

// ---------------------------------------------------------------------------
// P = pos_enc @ Wpos  (M=2047 guarded, bf16 out, row 2047 zeroed)
// ---------------------------------------------------------------------------
__global__ __launch_bounds__(256) void gemm_p_kernel(
    const float* __restrict__ A, const ushort_t* __restrict__ WTp,
    ushort_t* __restrict__ Po, int M)
{
    const int tid = threadIdx.x;
    const int col0 = blockIdx.x * 64;
    const int row0 = blockIdx.y * 64;
    const int w = tid >> 6, lane = tid & 63;
    const int quad = lane >> 4, lanelo = lane & 15;
    const int sr = tid >> 2, sc = (tid & 3) * 16;

    __shared__ ushort_t As[64][72];
    __shared__ ushort_t Ws[64][72];

    f32x4 acc[4] = {};

    for (int k0 = 0; k0 < 512; k0 += 64) {
        __syncthreads();
        {
            ushort_t tmp[16];
            if (row0 + sr < M) {
                const float* ap = A + (size_t)(row0 + sr) * 512 + k0 + sc;
                cvt4(*(const float4*)(ap + 0),  tmp + 0);
                cvt4(*(const float4*)(ap + 4),  tmp + 4);
                cvt4(*(const float4*)(ap + 8),  tmp + 8);
                cvt4(*(const float4*)(ap + 12), tmp + 12);
            } else {
                #pragma unroll
                for (int e = 0; e < 16; ++e) tmp[e] = 0;
            }
            *(s16x8*)&As[sr][sc]     = pack8(tmp);
            *(s16x8*)&As[sr][sc + 8] = pack8(tmp + 8);
        }
        {
            const ushort_t* wp = WTp + ((size_t)(col0 + sr)) * 512 + k0 + sc;
            *(s16x8*)&Ws[sr][sc]     = *(const s16x8*)wp;
            *(s16x8*)&Ws[sr][sc + 8] = *(const s16x8*)(wp + 8);
        }
        __syncthreads();

        #pragma unroll
        for (int ks = 0; ks < 2; ++ks) {
            s16x8 af = *(const s16x8*)&As[16 * w + lanelo][ks * 32 + quad * 8];
            #pragma unroll
            for (int tn = 0; tn < 4; ++tn) {
                s16x8 bf = *(const s16x8*)&Ws[tn * 16 + lanelo][ks * 32 + quad * 8];
                acc[tn] = mfma16(af, bf, acc[tn]);
            }
        }
    }

    #pragma unroll
    for (int tn = 0; tn < 4; ++tn) {
        int col = col0 + tn * 16 + lanelo;
        #pragma unroll
        for (int r = 0; r < 4; ++r) {
            int row = row0 + 16 * w + 4 * quad + r;
            Po[(size_t)row * 512 + col] = (row < M) ? f2bf(acc[tn][r]) : (ushort_t)0;
        }
    }
}

// ---------------------------------------------------------------------------
// MFMA flash attention with fused relative shift.
// Block: (t-tile of 64, h, b); 4 waves, wave w owns query rows [16w,16w+16).
// score[t,s] = (q+u)*0.125 . k[s]  +  (q+v)*0.125 . P[s - t + 1023]
// Pos part: G = Qv . Pwin^T over a 128-row P window; band G[row][col-row+63]
// is stored to LDS banded as Gb[row][col].
// ---------------------------------------------------------------------------
__global__ __launch_bounds__(256) void attn_mfma(
    const ushort_t* __restrict__ Qu, const ushort_t* __restrict__ Qv,
    const ushort_t* __restrict__ Kb, const ushort_t* __restrict__ Vb,
    const ushort_t* __restrict__ Pb,
    float* __restrict__ O)
{
    const int tid = threadIdx.x;
    const int t0 = blockIdx.x * 64;
    const int h  = blockIdx.y;
    const int b  = blockIdx.z;
    const int w = tid >> 6, lane = tid & 63;
    const int quad = lane >> 4, lanelo = lane & 15;
    const int sr = tid >> 2, sc = (tid & 3) * 16;

    __shared__ ushort_t Kt[64][72];     //  9216 B  [s][d]
    __shared__ ushort_t VtT[64][72];    //  9216 B  [d][s]
    __shared__ ushort_t Pt[128][72];    // 18432 B  [j][d]
    __shared__ float    Gb[64][68];     // 17408 B  banded pos scores
    __shared__ ushort_t Ps[64][72];     //  9216 B  probs (bf16)
                                        // total 63488 B

    // Q fragments (A-layout): rows t0 + 16w + lanelo, k = ks*32 + quad*8 + j
    const size_t qrow = (size_t)(b * T_SEQ + t0 + 16 * w + lanelo) * 512 + h * 64;
    s16x8 qu[2], qv[2];
    qu[0] = *(const s16x8*)(Qu + qrow + quad * 8);
    qu[1] = *(const s16x8*)(Qu + qrow + 32 + quad * 8);
    qv[0] = *(const s16x8*)(Qv + qrow + quad * 8);
    qv[1] = *(const s16x8*)(Qv + qrow + 32 + quad * 8);

    f32x4 acc_o[4] = {};
    float m_run[4], l_run[4];
    #pragma unroll
    for (int r = 0; r < 4; ++r) { m_run[r] = -1e30f; l_run[r] = 0.f; }

    for (int s0 = 0; s0 < T_SEQ; s0 += 64) {
        __syncthreads();
        {   // stage K, V(transposed), P window
            size_t gk = (size_t)(b * T_SEQ + s0 + sr) * 512 + h * 64 + sc;
            s16x8 k0v = *(const s16x8*)(Kb + gk);
            s16x8 k1v = *(const s16x8*)(Kb + gk + 8);
            *(s16x8*)&Kt[sr][sc]     = k0v;
            *(s16x8*)&Kt[sr][sc + 8] = k1v;
            s16x8 v0v = *(const s16x8*)(Vb + gk);
            s16x8 v1v = *(const s16x8*)(Vb + gk + 8);
            #pragma unroll
            for (int e = 0; e < 8; ++e) VtT[sc + e][sr]     = (ushort_t)v0v[e];
            #pragma unroll
            for (int e = 0; e < 8; ++e) VtT[sc + 8 + e][sr] = (ushort_t)v1v[e];

            const int pr0 = s0 - t0 + 960;           // >= 0, <= 1920
            size_t gp = (size_t)(pr0 + sr) * 512 + h * 64 + sc;
            *(s16x8*)&Pt[sr][sc]     = *(const s16x8*)(Pb + gp);
            *(s16x8*)&Pt[sr][sc + 8] = *(const s16x8*)(Pb + gp + 8);
            gp += (size_t)64 * 512;
            *(s16x8*)&Pt[sr + 64][sc]     = *(const s16x8*)(Pb + gp);
            *(s16x8*)&Pt[sr + 64][sc + 8] = *(const s16x8*)(Pb + gp + 8);
        }
        __syncthreads();

        f32x4 acc_c[4] = {};
        f32x4 acc_g[8] = {};
        #pragma unroll
        for (int ks = 0; ks < 2; ++ks) {
            #pragma unroll
            for (int tn = 0; tn < 4; ++tn) {
                s16x8 bf = *(const s16x8*)&Kt[tn * 16 + lanelo][ks * 32 + quad * 8];
                acc_c[tn] = mfma16(qu[ks], bf, acc_c[tn]);
            }
            #pragma unroll
            for (int jt = 0; jt < 8; ++jt) {
                s16x8 bf = *(const s16x8*)&Pt[jt * 16 + lanelo][ks * 32 + quad * 8];
                acc_g[jt] = mfma16(qv[ks], bf, acc_g[jt]);
            }
        }

        // write banded pos scores: Gb[row][col] = G[row][j], col = j - 63 + row
        #pragma unroll
        for (int jt = 0; jt < 8; ++jt)
            #pragma unroll
            for (int r = 0; r < 4; ++r) {
                int row = 16 * w + 4 * quad + r;
                int jj = 16 * jt + lanelo - 63 + row;
                if (jj >= 0 && jj < 64) Gb[row][jj] = acc_g[jt][r];
            }
        asm volatile("s_waitcnt lgkmcnt(0)" ::: "memory");

        // combine + online softmax (rows are wave-private strips)
        float m_new[4], alpha[4];
        float p[4][4];
        #pragma unroll
        for (int r = 0; r < 4; ++r) {
            int row = 16 * w + 4 * quad + r;
            float mx = -1e30f;
            #pragma unroll
            for (int tn = 0; tn < 4; ++tn) {
                float scv = acc_c[tn][r] + Gb[row][tn * 16 + lanelo];
                p[tn][r] = scv;
                mx = fmaxf(mx, scv);
            }
            mx = fmaxf(mx, __shfl_xor(mx, 1));
            mx = fmaxf(mx, __shfl_xor(mx, 2));
            mx = fmaxf(mx, __shfl_xor(mx, 4));
            mx = fmaxf(mx, __shfl_xor(mx, 8));
            m_new[r] = fmaxf(m_run[r], mx);
            alpha[r] = __expf(m_run[r] - m_new[r]);
            m_run[r] = m_new[r];
        }
        #pragma unroll
        for (int r = 0; r < 4; ++r) {
            float psum = 0.f;
            #pragma unroll
            for (int tn = 0; tn < 4; ++tn) {
                float e = __expf(p[tn][r] - m_new[r]);
                p[tn][r] = e;
                psum += e;
            }
            psum += __shfl_xor(psum, 1);
            psum += __shfl_xor(psum, 2);
            psum += __shfl_xor(psum, 4);
            psum += __shfl_xor(psum, 8);
            l_run[r] = l_run[r] * alpha[r] + psum;
        }
        #pragma unroll
        for (int tn = 0; tn < 4; ++tn)
            #pragma unroll
            for (int r = 0; r < 4; ++r)
                Ps[16 * w + 4 * quad + r][tn * 16 + lanelo] = f2bf(p[tn][r]);
        #pragma unroll
        for (int dt = 0; dt < 4; ++dt)
            #pragma unroll
            for (int r = 0; r < 4; ++r)
                acc_o[dt][r] *= alpha[r];
        asm volatile("s_waitcnt lgkmcnt(0)" ::: "memory");

        // PV: A = probs (A-layout from Ps), B = V^T tile
        #pragma unroll
        for (int ks = 0; ks < 2; ++ks) {
            s16x8 af = *(const s16x8*)&Ps[16 * w + lanelo][ks * 32 + quad * 8];
            #pragma unroll
            for (int dt = 0; dt < 4; ++dt) {
                s16x8 bf = *(const s16x8*)&VtT[dt * 16 + lanelo][ks * 32 + quad * 8];
                acc_o[dt] = mfma16(af, bf, acc_o[dt]);
            }
        }
    }

    #pragma unroll
    for (int r = 0; r < 4; ++r) {
        float inv = 1.0f / l_run[r];
        int row = t0 + 16 * w + 4 * quad + r;
        size_t base = (size_t)(b * T_SEQ + row) * 512 + h * 64;
        #pragma unroll
        for (int dt = 0; dt < 4; ++dt)
            O[base + dt * 16 + lanelo] = acc_o[dt][r] * inv;
    }
}

// ---------------------------------------------------------------------------
// fp32 tiled GEMM (round-1, proven) — final projection only.
// ---------------------------------------------------------------------------
__global__ __launch_bounds__(256) void gemm_bias_kernel(
    const float* __restrict__ A, const float* __restrict__ W,
    const float* __restrict__ bias, float* __restrict__ C,
    int M, int N, int K)
{
    const int tid  = threadIdx.x;
    const int row0 = blockIdx.y * 64;
    const int col0 = blockIdx.x * 64;

    __shared__ float As[16][64 + 1];
    __shared__ float Bs[16][64 + 1];

    const int ty = tid >> 4;
    const int tx = tid & 15;

    float acc[4][4] = {};

    for (int k0 = 0; k0 < K; k0 += 16) {
        #pragma unroll
        for (int l = 0; l < 4; ++l) {
            int idx = tid + l * 256;
            int r   = idx >> 4;
            int kk  = idx & 15;
            int gr  = row0 + r;
            As[kk][r] = (gr < M) ? A[(size_t)gr * K + k0 + kk] : 0.f;
        }
        #pragma unroll
        for (int l = 0; l < 4; ++l) {
            int idx = tid + l * 256;
            int kk  = idx >> 6;
            int c   = idx & 63;
            Bs[kk][c] = W[(size_t)(k0 + kk) * N + col0 + c];
        }
        __syncthreads();

        #pragma unroll
        for (int kk = 0; kk < 16; ++kk) {
            float a[4], bvv[4];
            #pragma unroll
            for (int i = 0; i < 4; ++i) a[i]   = As[kk][ty * 4 + i];
            #pragma unroll
            for (int j = 0; j < 4; ++j) bvv[j] = Bs[kk][tx * 4 + j];
            #pragma unroll
            for (int i = 0; i < 4; ++i)
                #pragma unroll
                for (int j = 0; j < 4; ++j)
                    acc[i][j] += a[i] * bvv[j];
        }
        __syncthreads();
    }

    #pragma unroll
    for (int i = 0; i < 4; ++i) {
        int gr = row0 + ty * 4 + i;
        if (gr >= M) continue;
        #pragma unroll
        for (int j = 0; j < 4; ++j) {
            int gc = col0 + tx * 4 + j;
            float v = acc[i][j];
            if (bias) v += bias[gc];
            C[(size_t)gr * N + gc] = v;
        }
    }
}

// ---------------------------------------------------------------------------
extern "C" void kernel_launch(void* const* d_in, const int* in_sizes, int n_in,
                              void* d_out, int out_size, void* d_ws, size_t ws_size,
                              hipStream_t stream) {
    const float* x       = (const float*)d_in[0];
    const float* pos_enc = (const float*)d_in[1];
    const float* Wq      = (const float*)d_in[2];
    const float* bq      = (const float*)d_in[3];
    const float* Wk      = (const float*)d_in[4];
    const float* bk      = (const float*)d_in[5];
    const float* Wv      = (const float*)d_in[6];
    const float* bv      = (const float*)d_in[7];
    const float* Wpos    = (const float*)d_in[8];
    const float* pbu     = (const float*)d_in[9];
    const float* pbv     = (const float*)d_in[10];
    const float* Wo      = (const float*)d_in[11];
    const float* bo      = (const float*)d_in[12];
    float* out = (float*)d_out;

    const size_t M  = 8 * T_SEQ;                 // 8192
    const size_t SZ = M * D_MODEL;               // 4,194,304

    char* ws = (char*)d_ws;
    ushort_t* Qu_b = (ushort_t*)ws;                         ws += SZ * 2;
    ushort_t* Qv_b = (ushort_t*)ws;                         ws += SZ * 2;
    ushort_t* K_b  = (ushort_t*)ws;                         ws += SZ * 2;
    ushort_t* V_b  = (ushort_t*)ws;                         ws += SZ * 2;
    ushort_t* P_b  = (ushort_t*)ws;                         ws += (size_t)2048 * 512 * 2;
    ushort_t* WT   = (ushort_t*)ws;                         ws += (size_t)4 * 512 * 512 * 2;
    float*    AO   = (float*)ws;                            ws += SZ * 4;

    dim3 blk(256);

    hipLaunchKernelGGL(transpose_cast_w, dim3(8, 8, 4), blk, 0, stream,
                       Wq, Wk, Wv, Wpos, WT);

    hipLaunchKernelGGL(gemm_qkv_fused, dim3(8, 128), blk, 0, stream,
                       x, WT, bq, bk, bv, pbu, pbv, Qu_b, Qv_b, K_b, V_b);

    hipLaunchKernelGGL(gemm_p_kernel, dim3(8, 32), blk, 0, stream,
                       pos_enc, WT + (size_t)3 * 512 * 512, P_b, 2047);

    hipLaunchKernelGGL(attn_mfma, dim3(16, 8, 8), blk, 0, stream,
                       Qu_b, Qv_b, K_b, V_b, P_b, AO);

    hipLaunchKernelGGL(gemm_bias_kernel, dim3(8, 128), blk, 0, stream,
                       AO, Wo, bo, out, (int)M, D_MODEL, D_MODEL);
}

// Round 3
// 257.944 us; speedup vs baseline: 13.0137x; 1.3992x over previous
//
#include <hip/hip_runtime.h>
#include <hip/hip_bf16.h>

#define T_SEQ 1024
#define D_MODEL 512
#define N_HEADS 8
#define D_HEAD 64

typedef unsigned short ushort_t;
typedef short s16x8 __attribute__((ext_vector_type(8)));
typedef float f32x4 __attribute__((ext_vector_type(4)));

__device__ inline f32x4 mfma16(s16x8 a, s16x8 b, f32x4 c) {
    return __builtin_amdgcn_mfma_f32_16x16x32_bf16(a, b, c, 0, 0, 0);
}

__device__ inline ushort_t f2bf(float f) {   // RTNE float->bf16
    union { float f; unsigned u; } v; v.f = f;
    unsigned r = v.u + 0x7FFFu + ((v.u >> 16) & 1u);
    return (ushort_t)(r >> 16);
}
__device__ inline void cvt4(const float4 f, ushort_t* t) {
    t[0] = f2bf(f.x); t[1] = f2bf(f.y); t[2] = f2bf(f.z); t[3] = f2bf(f.w);
}
__device__ inline s16x8 pack8(const ushort_t* t) {
    s16x8 r;
    #pragma unroll
    for (int e = 0; e < 8; ++e) r[e] = (short)t[e];
    return r;
}

// ---------------------------------------------------------------------------
// Pre-cast x (8192x512) and pos_enc (2047x512, row 2047 zeroed) to bf16.
// One thread = 8 elements.
// ---------------------------------------------------------------------------
__global__ __launch_bounds__(256) void cast_inputs(
    const float* __restrict__ x, const float* __restrict__ pos,
    ushort_t* __restrict__ xb, ushort_t* __restrict__ posb)
{
    const size_t N1 = (size_t)8192 * 512;
    size_t e = ((size_t)blockIdx.x * 256 + threadIdx.x) * 8;
    ushort_t tmp[8];
    if (e < N1) {
        const float4* s = (const float4*)(x + e);
        cvt4(s[0], tmp); cvt4(s[1], tmp + 4);
        *(s16x8*)(xb + e) = pack8(tmp);
    } else {
        size_t e2 = e - N1;                 // < 2048*512
        int row = (int)(e2 >> 9);
        if (row < 2047) {
            const float4* s = (const float4*)(pos + e2);
            cvt4(s[0], tmp); cvt4(s[1], tmp + 4);
        } else {
            #pragma unroll
            for (int i = 0; i < 8; ++i) tmp[i] = 0;
        }
        *(s16x8*)(posb + e2) = pack8(tmp);
    }
}

// ---------------------------------------------------------------------------
// Transpose+cast weights: WT[z][n][k] = bf16(W[k][n]), 512x512, z=0..4
// ---------------------------------------------------------------------------
__global__ __launch_bounds__(256) void transpose_cast_w(
    const float* __restrict__ W0, const float* __restrict__ W1,
    const float* __restrict__ W2, const float* __restrict__ W3,
    const float* __restrict__ W4, ushort_t* __restrict__ WT)
{
    const float* W = (blockIdx.z == 0) ? W0 : (blockIdx.z == 1) ? W1
                   : (blockIdx.z == 2) ? W2 : (blockIdx.z == 3) ? W3 : W4;
    __shared__ float T[64][68];
    const int n0 = blockIdx.x * 64, k0 = blockIdx.y * 64;
    const int tid = threadIdx.x;
    const int rr = tid >> 2, cc = (tid & 3) * 16;

    const float* src = W + (size_t)(k0 + rr) * 512 + n0 + cc;
    *(float4*)&T[rr][cc + 0]  = *(const float4*)(src);
    *(float4*)&T[rr][cc + 4]  = *(const float4*)(src + 4);
    *(float4*)&T[rr][cc + 8]  = *(const float4*)(src + 8);
    *(float4*)&T[rr][cc + 12] = *(const float4*)(src + 12);
    __syncthreads();

    ushort_t tmp[16];
    #pragma unroll
    for (int e = 0; e < 16; ++e) tmp[e] = f2bf(T[cc + e][rr]);
    ushort_t* dst = WT + ((size_t)blockIdx.z * 512 + n0 + rr) * 512 + k0 + cc;
    *(s16x8*)dst       = pack8(tmp);
    *(s16x8*)(dst + 8) = pack8(tmp + 8);
}

// ---------------------------------------------------------------------------
// Fused Q/K/V MFMA GEMM. A = xb bf16 [8192][512]; WT bf16 [set][n][k].
// Q epilogue: Qu=(acc+bq+pbu)*0.125, Qv=(acc+bq+pbv)*0.125 (bf16).
// V epilogue writes V^T layout: VoT[((b*8+h)*64+d)][t]  (ushort4, t-packed).
// ---------------------------------------------------------------------------
__global__ __launch_bounds__(256) void gemm_qkv_fused(
    const ushort_t* __restrict__ A, const ushort_t* __restrict__ WT,
    const float* __restrict__ bq, const float* __restrict__ bk,
    const float* __restrict__ bv,
    const float* __restrict__ pbu, const float* __restrict__ pbv,
    ushort_t* __restrict__ Qu, ushort_t* __restrict__ Qv,
    ushort_t* __restrict__ Ko, ushort_t* __restrict__ VoT)
{
    const int tid = threadIdx.x;
    const int col0 = blockIdx.x * 64;
    const int row0 = blockIdx.y * 64;
    const int w = tid >> 6, lane = tid & 63;
    const int quad = lane >> 4, lanelo = lane & 15;
    const int sr = tid >> 2, sc = (tid & 3) * 16;

    __shared__ ushort_t As[64][72];
    __shared__ ushort_t Ws[3][64][72];

    f32x4 acc[3][4] = {};

    for (int k0 = 0; k0 < 512; k0 += 64) {
        __syncthreads();
        {
            const ushort_t* ap = A + (size_t)(row0 + sr) * 512 + k0 + sc;
            *(s16x8*)&As[sr][sc]     = *(const s16x8*)ap;
            *(s16x8*)&As[sr][sc + 8] = *(const s16x8*)(ap + 8);
        }
        #pragma unroll
        for (int s = 0; s < 3; ++s) {
            const ushort_t* wp = WT + ((size_t)(s * 512 + col0 + sr)) * 512 + k0 + sc;
            *(s16x8*)&Ws[s][sr][sc]     = *(const s16x8*)wp;
            *(s16x8*)&Ws[s][sr][sc + 8] = *(const s16x8*)(wp + 8);
        }
        __syncthreads();

        #pragma unroll
        for (int ks = 0; ks < 2; ++ks) {
            s16x8 af = *(const s16x8*)&As[16 * w + lanelo][ks * 32 + quad * 8];
            #pragma unroll
            for (int s = 0; s < 3; ++s)
                #pragma unroll
                for (int tn = 0; tn < 4; ++tn) {
                    s16x8 bf = *(const s16x8*)&Ws[s][tn * 16 + lanelo][ks * 32 + quad * 8];
                    acc[s][tn] = mfma16(af, bf, acc[s][tn]);
                }
        }
    }

    const int b_idx = row0 >> 10;          // block rows never cross batch
    const int h_idx = col0 >> 6;           // block cols never cross head
    const int tbase = (row0 & 1023) + 16 * w + 4 * quad;

    #pragma unroll
    for (int tn = 0; tn < 4; ++tn) {
        int col = col0 + tn * 16 + lanelo;
        int d   = tn * 16 + lanelo;
        float vbq = bq[col], vbu = pbu[col], vbv = pbv[col];
        float vbk = bk[col], vbb = bv[col];
        #pragma unroll
        for (int r = 0; r < 4; ++r) {
            int row = row0 + 16 * w + 4 * quad + r;
            size_t o = (size_t)row * 512 + col;
            float aq = acc[0][tn][r] + vbq;
            Qu[o] = f2bf((aq + vbu) * 0.125f);
            Qv[o] = f2bf((aq + vbv) * 0.125f);
            Ko[o] = f2bf(acc[1][tn][r] + vbk);
        }
        ushort4 vp;
        vp.x = f2bf(acc[2][tn][0] + vbb);
        vp.y = f2bf(acc[2][tn][1] + vbb);
        vp.z = f2bf(acc[2][tn][2] + vbb);
        vp.w = f2bf(acc[2][tn][3] + vbb);
        *(ushort4*)(VoT + ((size_t)((b_idx * 8 + h_idx) * 64 + d)) * 1024 + tbase) = vp;
    }
}

// ---------------------------------------------------------------------------
// P = posb @ Wpos^T-staged  (bf16 in/out, M=2048, row 2047 of posb is zero)
// ---------------------------------------------------------------------------
__global__ __launch_bounds__(256) void gemm_p_kernel(
    const ushort_t* __restrict__ A, const ushort_t* __restrict__ WTp,
    ushort_t* __restrict__ Po)
{
    const int tid = threadIdx.x;
    const int col0 = blockIdx.x * 64;
    const int row0 = blockIdx.y * 64;
    const int w = tid >> 6, lane = tid & 63;
    const int quad = lane >> 4, lanelo = lane & 15;
    const int sr = tid >> 2, sc = (tid & 3) * 16;

    __shared__ ushort_t As[64][72];
    __shared__ ushort_t Ws[64][72];

    f32x4 acc[4] = {};

    for (int k0 = 0; k0 < 512; k0 += 64) {
        __syncthreads();
        {
            const ushort_t* ap = A + (size_t)(row0 + sr) * 512 + k0 + sc;
            *(s16x8*)&As[sr][sc]     = *(const s16x8*)ap;
            *(s16x8*)&As[sr][sc + 8] = *(const s16x8*)(ap + 8);
        }
        {
            const ushort_t* wp = WTp + ((size_t)(col0 + sr)) * 512 + k0 + sc;
            *(s16x8*)&Ws[sr][sc]     = *(const s16x8*)wp;
            *(s16x8*)&Ws[sr][sc + 8] = *(const s16x8*)(wp + 8);
        }
        __syncthreads();

        #pragma unroll
        for (int ks = 0; ks < 2; ++ks) {
            s16x8 af = *(const s16x8*)&As[16 * w + lanelo][ks * 32 + quad * 8];
            #pragma unroll
            for (int tn = 0; tn < 4; ++tn) {
                s16x8 bf = *(const s16x8*)&Ws[tn * 16 + lanelo][ks * 32 + quad * 8];
                acc[tn] = mfma16(af, bf, acc[tn]);
            }
        }
    }

    #pragma unroll
    for (int tn = 0; tn < 4; ++tn) {
        int col = col0 + tn * 16 + lanelo;
        #pragma unroll
        for (int r = 0; r < 4; ++r) {
            int row = row0 + 16 * w + 4 * quad + r;
            Po[(size_t)row * 512 + col] = f2bf(acc[tn][r]);
        }
    }
}

// ---------------------------------------------------------------------------
// Final projection: out = AOb @ WoT + bo  (A bf16, fp32 out)
// ---------------------------------------------------------------------------
__global__ __launch_bounds__(256) void gemm_out_kernel(
    const ushort_t* __restrict__ A, const ushort_t* __restrict__ WTo,
    const float* __restrict__ bias, float* __restrict__ C)
{
    const int tid = threadIdx.x;
    const int col0 = blockIdx.x * 64;
    const int row0 = blockIdx.y * 64;
    const int w = tid >> 6, lane = tid & 63;
    const int quad = lane >> 4, lanelo = lane & 15;
    const int sr = tid >> 2, sc = (tid & 3) * 16;

    __shared__ ushort_t As[64][72];
    __shared__ ushort_t Ws[64][72];

    f32x4 acc[4] = {};

    for (int k0 = 0; k0 < 512; k0 += 64) {
        __syncthreads();
        {
            const ushort_t* ap = A + (size_t)(row0 + sr) * 512 + k0 + sc;
            *(s16x8*)&As[sr][sc]     = *(const s16x8*)ap;
            *(s16x8*)&As[sr][sc + 8] = *(const s16x8*)(ap + 8);
        }
        {
            const ushort_t* wp = WTo + ((size_t)(col0 + sr)) * 512 + k0 + sc;
            *(s16x8*)&Ws[sr][sc]     = *(const s16x8*)wp;
            *(s16x8*)&Ws[sr][sc + 8] = *(const s16x8*)(wp + 8);
        }
        __syncthreads();

        #pragma unroll
        for (int ks = 0; ks < 2; ++ks) {
            s16x8 af = *(const s16x8*)&As[16 * w + lanelo][ks * 32 + quad * 8];
            #pragma unroll
            for (int tn = 0; tn < 4; ++tn) {
                s16x8 bf = *(const s16x8*)&Ws[tn * 16 + lanelo][ks * 32 + quad * 8];
                acc[tn] = mfma16(af, bf, acc[tn]);
            }
        }
    }

    #pragma unroll
    for (int tn = 0; tn < 4; ++tn) {
        int col = col0 + tn * 16 + lanelo;
        float vb = bias[col];
        #pragma unroll
        for (int r = 0; r < 4; ++r) {
            int row = row0 + 16 * w + 4 * quad + r;
            C[(size_t)row * 512 + col] = acc[tn][r] + vb;
        }
    }
}

// ---------------------------------------------------------------------------
// MFMA flash attention, fused relative shift, register band extraction.
// Block: (64 q-rows, h, b); wave w owns rows [16w,16w+16).
// Pos scores: each wave computes only jt in [3-w, 7-w] (5 tiles), then the
// band value G[row][j], j=16(tn-w)+u, u=lanelo+63-4quad-r, comes from
// lane 16*quad+(u&15), register tile tn+(u>>4)-3 via two shuffles + select.
// ---------------------------------------------------------------------------
__global__ __launch_bounds__(256) void attn_mfma(
    const ushort_t* __restrict__ Qu, const ushort_t* __restrict__ Qv,
    const ushort_t* __restrict__ Kb, const ushort_t* __restrict__ VT,
    const ushort_t* __restrict__ Pb,
    ushort_t* __restrict__ AOb)
{
    const int tid = threadIdx.x;
    const int t0 = blockIdx.x * 64;
    const int h  = blockIdx.y;
    const int b  = blockIdx.z;
    const int w = tid >> 6, lane = tid & 63;
    const int quad = lane >> 4, lanelo = lane & 15;
    const int sr = tid >> 2, sc = (tid & 3) * 16;

    __shared__ ushort_t Kt[64][72];     //  9216 B  [s][d]
    __shared__ ushort_t VtT[64][72];    //  9216 B  [d][s]
    __shared__ ushort_t Pt[128][72];    // 18432 B  [j][d]
    __shared__ ushort_t Ps[64][72];     //  9216 B  probs / final O staging
                                        // total 46080 B -> 3 blocks/CU

    const size_t qrow = (size_t)(b * T_SEQ + t0 + 16 * w + lanelo) * 512 + h * 64;
    s16x8 qu[2], qv[2];
    qu[0] = *(const s16x8*)(Qu + qrow + quad * 8);
    qu[1] = *(const s16x8*)(Qu + qrow + 32 + quad * 8);
    qv[0] = *(const s16x8*)(Qv + qrow + quad * 8);
    qv[1] = *(const s16x8*)(Qv + qrow + 32 + quad * 8);

    f32x4 acc_o[4] = {};
    float m_run[4], l_run[4];
    #pragma unroll
    for (int r = 0; r < 4; ++r) { m_run[r] = -1e30f; l_run[r] = 0.f; }

    const int u_base = lanelo + 63 - 4 * quad;     // u = u_base - r in [48,78]
    const ushort_t* VTbh = VT + ((size_t)((b * 8 + h) * 64)) * 1024;

    for (int s0 = 0; s0 < T_SEQ; s0 += 64) {
        __syncthreads();
        {   // stage K [s][d]
            size_t gk = (size_t)(b * T_SEQ + s0 + sr) * 512 + h * 64 + sc;
            *(s16x8*)&Kt[sr][sc]     = *(const s16x8*)(Kb + gk);
            *(s16x8*)&Kt[sr][sc + 8] = *(const s16x8*)(Kb + gk + 8);
        }
        {   // stage V^T [d][s] straight from pre-transposed global layout
            const ushort_t* vp = VTbh + (size_t)sr * 1024 + s0 + sc;
            *(s16x8*)&VtT[sr][sc]     = *(const s16x8*)vp;
            *(s16x8*)&VtT[sr][sc + 8] = *(const s16x8*)(vp + 8);
        }
        {   // stage 128-row P window
            const int pr0 = s0 - t0 + 960;          // in [0, 1920]
            size_t gp = (size_t)(pr0 + sr) * 512 + h * 64 + sc;
            *(s16x8*)&Pt[sr][sc]     = *(const s16x8*)(Pb + gp);
            *(s16x8*)&Pt[sr][sc + 8] = *(const s16x8*)(Pb + gp + 8);
            gp += (size_t)64 * 512;
            *(s16x8*)&Pt[sr + 64][sc]     = *(const s16x8*)(Pb + gp);
            *(s16x8*)&Pt[sr + 64][sc + 8] = *(const s16x8*)(Pb + gp + 8);
        }
        __syncthreads();

        f32x4 acc_c[4] = {};
        f32x4 acc_g[5] = {};
        #pragma unroll
        for (int ks = 0; ks < 2; ++ks) {
            #pragma unroll
            for (int tn = 0; tn < 4; ++tn) {
                s16x8 bf = *(const s16x8*)&Kt[tn * 16 + lanelo][ks * 32 + quad * 8];
                acc_c[tn] = mfma16(qu[ks], bf, acc_c[tn]);
            }
            #pragma unroll
            for (int i = 0; i < 5; ++i) {   // jt = 3 - w + i
                s16x8 bf = *(const s16x8*)&Pt[(3 - w + i) * 16 + lanelo][ks * 32 + quad * 8];
                acc_g[i] = mfma16(qv[ks], bf, acc_g[i]);
            }
        }

        // band extraction + online softmax
        float p[4][4];
        float m_new[4], alpha[4];
        #pragma unroll
        for (int r = 0; r < 4; ++r) {
            int u = u_base - r;
            int srcl = (quad << 4) | (u & 15);
            bool hi = (u >= 64);
            float mx = -1e30f;
            #pragma unroll
            for (int tn = 0; tn < 4; ++tn) {
                float v0 = __shfl(acc_g[tn][r], srcl);
                float v1 = __shfl(acc_g[tn + 1][r], srcl);
                float scv = acc_c[tn][r] + (hi ? v1 : v0);
                p[tn][r] = scv;
                mx = fmaxf(mx, scv);
            }
            mx = fmaxf(mx, __shfl_xor(mx, 1));
            mx = fmaxf(mx, __shfl_xor(mx, 2));
            mx = fmaxf(mx, __shfl_xor(mx, 4));
            mx = fmaxf(mx, __shfl_xor(mx, 8));
            m_new[r] = fmaxf(m_run[r], mx);
            alpha[r] = __expf(m_run[r] - m_new[r]);
            m_run[r] = m_new[r];
        }
        #pragma unroll
        for (int r = 0; r < 4; ++r) {
            float psum = 0.f;
            #pragma unroll
            for (int tn = 0; tn < 4; ++tn) {
                float e = __expf(p[tn][r] - m_new[r]);
                p[tn][r] = e;
                psum += e;
            }
            psum += __shfl_xor(psum, 1);
            psum += __shfl_xor(psum, 2);
            psum += __shfl_xor(psum, 4);
            psum += __shfl_xor(psum, 8);
            l_run[r] = l_run[r] * alpha[r] + psum;
        }
        #pragma unroll
        for (int tn = 0; tn < 4; ++tn)
            #pragma unroll
            for (int r = 0; r < 4; ++r)
                Ps[16 * w + 4 * quad + r][tn * 16 + lanelo] = f2bf(p[tn][r]);
        #pragma unroll
        for (int dt = 0; dt < 4; ++dt)
            #pragma unroll
            for (int r = 0; r < 4; ++r)
                acc_o[dt][r] *= alpha[r];
        asm volatile("s_waitcnt lgkmcnt(0)" ::: "memory");

        // PV: A = probs (wave-private rows of Ps), B = V^T tile
        #pragma unroll
        for (int ks = 0; ks < 2; ++ks) {
            s16x8 af = *(const s16x8*)&Ps[16 * w + lanelo][ks * 32 + quad * 8];
            #pragma unroll
            for (int dt = 0; dt < 4; ++dt) {
                s16x8 bf = *(const s16x8*)&VtT[dt * 16 + lanelo][ks * 32 + quad * 8];
                acc_o[dt] = mfma16(af, bf, acc_o[dt]);
            }
        }
    }

    // epilogue: stage O into Ps (bf16), then coalesced vector stores
    __syncthreads();
    #pragma unroll
    for (int r = 0; r < 4; ++r) {
        float inv = 1.0f / l_run[r];
        #pragma unroll
        for (int dt = 0; dt < 4; ++dt)
            Ps[16 * w + 4 * quad + r][dt * 16 + lanelo] = f2bf(acc_o[dt][r] * inv);
    }
    __syncthreads();
    {
        ushort_t* dst = AOb + (size_t)(b * T_SEQ + t0 + sr) * 512 + h * 64 + sc;
        *(s16x8*)dst       = *(const s16x8*)&Ps[sr][sc];
        *(s16x8*)(dst + 8) = *(const s16x8*)&Ps[sr][sc + 8];
    }
}

// ---------------------------------------------------------------------------
extern "C" void kernel_launch(void* const* d_in, const int* in_sizes, int n_in,
                              void* d_out, int out_size, void* d_ws, size_t ws_size,
                              hipStream_t stream) {
    const float* x       = (const float*)d_in[0];
    const float* pos_enc = (const float*)d_in[1];
    const float* Wq      = (const float*)d_in[2];
    const float* bq      = (const float*)d_in[3];
    const float* Wk      = (const float*)d_in[4];
    const float* bk      = (const float*)d_in[5];
    const float* Wv      = (const float*)d_in[6];
    const float* bv      = (const float*)d_in[7];
    const float* Wpos    = (const float*)d_in[8];
    const float* pbu     = (const float*)d_in[9];
    const float* pbv     = (const float*)d_in[10];
    const float* Wo      = (const float*)d_in[11];
    const float* bo      = (const float*)d_in[12];
    float* out = (float*)d_out;

    const size_t M  = 8 * T_SEQ;                 // 8192
    const size_t SZ = M * D_MODEL;               // 4,194,304

    char* ws = (char*)d_ws;
    ushort_t* xb   = (ushort_t*)ws;              ws += SZ * 2;
    ushort_t* posb = (ushort_t*)ws;              ws += (size_t)2048 * 512 * 2;
    ushort_t* Qu_b = (ushort_t*)ws;              ws += SZ * 2;
    ushort_t* Qv_b = (ushort_t*)ws;              ws += SZ * 2;
    ushort_t* K_b  = (ushort_t*)ws;              ws += SZ * 2;
    ushort_t* VT_b = (ushort_t*)ws;              ws += SZ * 2;
    ushort_t* P_b  = (ushort_t*)ws;              ws += (size_t)2048 * 512 * 2;
    ushort_t* WT   = (ushort_t*)ws;              ws += (size_t)5 * 512 * 512 * 2;
    ushort_t* AOb  = (ushort_t*)ws;              ws += SZ * 2;

    dim3 blk(256);

    hipLaunchKernelGGL(cast_inputs, dim3((unsigned)((SZ + 2048 * 512) / 8 / 256)), blk, 0, stream,
                       x, pos_enc, xb, posb);

    hipLaunchKernelGGL(transpose_cast_w, dim3(8, 8, 5), blk, 0, stream,
                       Wq, Wk, Wv, Wpos, Wo, WT);

    hipLaunchKernelGGL(gemm_qkv_fused, dim3(8, 128), blk, 0, stream,
                       xb, WT, bq, bk, bv, pbu, pbv, Qu_b, Qv_b, K_b, VT_b);

    hipLaunchKernelGGL(gemm_p_kernel, dim3(8, 32), blk, 0, stream,
                       posb, WT + (size_t)3 * 512 * 512, P_b);

    hipLaunchKernelGGL(attn_mfma, dim3(16, 8, 8), blk, 0, stream,
                       Qu_b, Qv_b, K_b, VT_b, P_b, AOb);

    hipLaunchKernelGGL(gemm_out_kernel, dim3(8, 128), blk, 0, stream,
                       AOb, WT + (size_t)4 * 512 * 512, bo, out);
}